// Round 2
// baseline (664.211 us; speedup 1.0000x reference)
//
#include <hip/hip_runtime.h>

#define U 4096
#define S 8192
#define D 32
#define NUM_REGIONS 128
#define GA 0.1f

#define TU 32      // users per block
#define TI 512     // items per block (2 per thread)
#define THREADS 256
#define GRID_X (U / TU)   // 128
#define GRID_Y (S / TI)   // 16
#define NBLOCKS (GRID_X * GRID_Y)

// ---------------- region loss: single block, LDS segment sums ----------------
// Also zero-inits loss_acc and done-counter for the mse kernel (stream-ordered
// before it), eliminating the memset node and the finalize dispatch.

__global__ __launch_bounds__(1024) void region_kernel(
    const float* __restrict__ user_emb,
    const int* __restrict__ region_index,
    float* __restrict__ rl_acc,
    float* __restrict__ loss_acc,
    unsigned int* __restrict__ done_counter) {
    __shared__ float sum_lds[NUM_REGIONS * D];  // 16 KB
    __shared__ float cnt_lds[NUM_REGIONS];
    __shared__ float wred[16];

    const int tid = threadIdx.x;

    // zero LDS tables
    for (int i = tid; i < NUM_REGIONS * D; i += 1024) sum_lds[i] = 0.0f;
    if (tid < NUM_REGIONS) cnt_lds[tid] = 0.0f;
    __syncthreads();

    // counts
    for (int u = tid; u < U; u += 1024)
        atomicAdd(&cnt_lds[region_index[u]], 1.0f);
    // sums
    for (int idx = tid; idx < U * D; idx += 1024) {
        int u = idx >> 5, d = idx & (D - 1);
        atomicAdd(&sum_lds[region_index[u] * D + d], user_emb[idx]);
    }
    __syncthreads();

    // leave-one-out deviation
    float local = 0.0f;
    for (int idx = tid; idx < U * D; idx += 1024) {
        int u = idx >> 5, d = idx & (D - 1);
        int r = region_index[u];
        float c = cnt_lds[r];
        if (c > 1.0f) {
            float e = user_emb[idx];
            float loo = (sum_lds[r * D + d] - e) / fmaxf(c - 1.0f, 1.0f);
            local += fabsf(e - loo);
        }
    }
    #pragma unroll
    for (int off = 32; off > 0; off >>= 1) local += __shfl_down(local, off, 64);
    int lane = tid & 63, wid = tid >> 6;
    if (lane == 0) wred[wid] = local;
    __syncthreads();
    if (tid == 0) {
        float t = 0.0f;
        #pragma unroll
        for (int i = 0; i < 16; i++) t += wred[i];
        rl_acc[0] = t;
        loss_acc[0] = 0.0f;
        done_counter[0] = 0u;
    }
}

// ---------------- main masked-MSE kernel (prefetch-pipelined) ----------------

__global__ __launch_bounds__(THREADS) void mse_kernel(
    const float* __restrict__ user_emb,
    const float* __restrict__ item_emb,
    const int* __restrict__ train_mask,
    const float* __restrict__ true_qos,
    const float* __restrict__ us_lossweight,
    float* __restrict__ loss_acc,
    const float* __restrict__ rl_acc,
    unsigned int* __restrict__ done_counter,
    float* __restrict__ out) {
    __shared__ float uemb[TU][D];  // 4 KB user tile

    const int ub = blockIdx.x * TU;
    const int sb = blockIdx.y * TI;

    // cooperative load of user tile: TU*D = 1024 floats = 256 float4
    {
        const float4* src = (const float4*)(user_emb + (size_t)ub * D);
        ((float4*)&uemb[0][0])[threadIdx.x] = src[threadIdx.x];
    }
    __syncthreads();

    const int s0 = sb + 2 * threadIdx.x;  // this thread's 2 items

    // item rows into registers (item_emb is 1 MiB total — L2/LLC resident)
    float4 ir0[8], ir1[8];
    {
        const float4* ip0 = (const float4*)(item_emb + (size_t)s0 * D);
        const float4* ip1 = (const float4*)(item_emb + (size_t)(s0 + 1) * D);
        #pragma unroll
        for (int k = 0; k < 8; k++) { ir0[k] = ip0[k]; ir1[k] = ip1[k]; }
    }

    // software pipeline: loads for iteration uu+1 in flight during compute of uu
    size_t base = (size_t)ub * S + s0;
    int2   m = *(const int2*)(train_mask + base);
    float2 q = *(const float2*)(true_qos + base);
    float2 w = *(const float2*)(us_lossweight + base);

    float acc = 0.0f;
    #pragma unroll 1
    for (int uu = 0; uu < TU; uu++) {
        size_t nbase = base + (uu < TU - 1 ? (size_t)S : 0);  // branch-free clamp
        int2   mn = *(const int2*)(train_mask + nbase);
        float2 qn = *(const float2*)(true_qos + nbase);
        float2 wn = *(const float2*)(us_lossweight + nbase);

        float d0 = 0.0f, d1 = 0.0f;
        const float4* ur = (const float4*)&uemb[uu][0];  // broadcast LDS reads
        #pragma unroll
        for (int k = 0; k < 8; k++) {
            float4 uv = ur[k];
            d0 += uv.x * ir0[k].x + uv.y * ir0[k].y + uv.z * ir0[k].z + uv.w * ir0[k].w;
            d1 += uv.x * ir1[k].x + uv.y * ir1[k].y + uv.z * ir1[k].z + uv.w * ir1[k].w;
        }
        float p0 = d0 * (float)m.x;
        float p1 = d1 * (float)m.y;
        float e0 = p0 - q.x;
        float e1 = p1 - q.y;
        acc += w.x * e0 * e0 + w.y * e1 * e1;

        m = mn; q = qn; w = wn; base = nbase;
    }

    // wave64 reduce + one atomic per block
    #pragma unroll
    for (int off = 32; off > 0; off >>= 1) acc += __shfl_down(acc, off, 64);
    __shared__ float wp[THREADS / 64];
    int lane = threadIdx.x & 63, wid = threadIdx.x >> 6;
    if (lane == 0) wp[wid] = acc;
    __syncthreads();
    if (threadIdx.x == 0) {
        float t = 0.0f;
        #pragma unroll
        for (int i = 0; i < THREADS / 64; i++) t += wp[i];
        atomicAdd(loss_acc, t);
        __threadfence();
        unsigned int n = atomicAdd(done_counter, 1u);
        if (n == NBLOCKS - 1) {
            // last block: all loss_acc adds are visible (fence + atomic order).
            float total = atomicAdd(loss_acc, 0.0f);          // coherent read
            float rl    = atomicAdd((float*)rl_acc, 0.0f);    // coherent read
            out[0] = total + GA * rl;
        }
    }
}

extern "C" void kernel_launch(void* const* d_in, const int* in_sizes, int n_in,
                              void* d_out, int out_size, void* d_ws, size_t ws_size,
                              hipStream_t stream) {
    const float* user_emb      = (const float*)d_in[0];
    const float* item_emb      = (const float*)d_in[1];
    const int*   train_mask    = (const int*)d_in[2];
    const float* true_qos      = (const float*)d_in[3];
    const float* us_lossweight = (const float*)d_in[4];
    const int*   region_index  = (const int*)d_in[5];
    float* out = (float*)d_out;

    float* ws            = (float*)d_ws;
    float* rl_acc        = ws;
    float* loss_acc      = ws + 1;
    unsigned int* done_counter = (unsigned int*)(ws + 2);

    region_kernel<<<1, 1024, 0, stream>>>(user_emb, region_index,
                                          rl_acc, loss_acc, done_counter);

    dim3 grid(GRID_X, GRID_Y);
    mse_kernel<<<grid, THREADS, 0, stream>>>(
        user_emb, item_emb, train_mask, true_qos, us_lossweight,
        loss_acc, rl_acc, done_counter, out);
}

// Round 3
// 578.624 us; speedup vs baseline: 1.1479x; 1.1479x over previous
//
#include <hip/hip_runtime.h>

#define U 4096
#define S 8192
#define D 32
#define NUM_REGIONS 128
#define GA 0.1f

#define TU 32      // users per block
#define TI 512     // items per block (2 per thread)
#define THREADS 256
#define GRID_X (U / TU)   // 128
#define GRID_Y (S / TI)   // 16
#define NBLOCKS (GRID_X * GRID_Y)

// ---------------- K1: per-region sums/counts, no atomics ----------------
// One block per region. thread = (group g = tid>>5, dim d = tid&31).
// Group g scans users u = g, g+8, ... ; lanes of a group broadcast-read
// region_index[u] (L2-resident, 16 KB). Also zero-inits loss_acc / done.

__global__ __launch_bounds__(256) void region_stats_kernel(
    const float* __restrict__ user_emb,
    const int* __restrict__ region_index,
    float* __restrict__ sums,      // [R, D]
    float* __restrict__ counts,    // [R]
    float* __restrict__ loss_acc,
    unsigned int* __restrict__ done_counter) {
    const int r = blockIdx.x;
    const int d = threadIdx.x & 31;
    const int g = threadIdx.x >> 5;

    float psum = 0.0f, pcnt = 0.0f;
    for (int u = g; u < U; u += 8) {
        if (region_index[u] == r) {
            psum += user_emb[u * D + d];
            pcnt += 1.0f;
        }
    }
    __shared__ float red[8][32];
    red[g][d] = psum;
    __syncthreads();
    if (g == 0) {
        float s = 0.0f;
        #pragma unroll
        for (int i = 0; i < 8; i++) s += red[i][d];
        sums[r * D + d] = s;
    }
    __syncthreads();
    red[g][d] = pcnt;
    __syncthreads();
    if (threadIdx.x == 0) {
        float c = 0.0f;
        #pragma unroll
        for (int i = 0; i < 8; i++) c += red[i][0];
        counts[r] = c;
        if (r == 0) { loss_acc[0] = 0.0f; done_counter[0] = 0u; }
    }
}

// ---------------- K2: masked-MSE + fused region loss + finalize ----------------

__device__ __forceinline__ float dot4(float4 a, float4 b) {
    return a.x * b.x + a.y * b.y + a.z * b.z + a.w * b.w;
}

__global__ __launch_bounds__(THREADS, 4) void mse_kernel(
    const float* __restrict__ user_emb,
    const float* __restrict__ item_emb,
    const int* __restrict__ train_mask,
    const float* __restrict__ true_qos,
    const float* __restrict__ us_lossweight,
    const int* __restrict__ region_index,
    const float* __restrict__ sums,
    const float* __restrict__ counts,
    float* __restrict__ loss_acc,
    unsigned int* __restrict__ done_counter,
    float* __restrict__ out) {
    __shared__ float uemb[TU][D];  // 4 KB user tile

    const int ub = blockIdx.x * TU;
    const int sb = blockIdx.y * TI;

    // stage user tile: TU*D = 1024 floats = 256 float4
    {
        const float4* src = (const float4*)(user_emb + (size_t)ub * D);
        ((float4*)&uemb[0][0])[threadIdx.x] = src[threadIdx.x];
    }
    __syncthreads();

    const int s0 = sb + 2 * threadIdx.x;  // this thread's 2 items

    // item rows in registers — 64 VGPRs; launch_bounds(256,4) caps at 128 so
    // the compiler keeps them resident instead of re-loading in the loop.
    float4 ir0[8], ir1[8];
    {
        const float4* ip0 = (const float4*)(item_emb + (size_t)s0 * D);
        const float4* ip1 = (const float4*)(item_emb + (size_t)(s0 + 1) * D);
        #pragma unroll
        for (int k = 0; k < 8; k++) { ir0[k] = ip0[k]; ir1[k] = ip1[k]; }
    }

    float acc = 0.0f;

    // fused region loss: the y==0 slab covers its 32 users (rows already in LDS)
    if (blockIdx.y == 0) {
        for (int i = threadIdx.x; i < TU * D; i += THREADS) {
            int uu = i >> 5, d = i & 31;
            int r = region_index[ub + uu];
            float c = counts[r];
            if (c > 1.0f) {
                float e = uemb[uu][d];
                float loo = (sums[r * D + d] - e) / fmaxf(c - 1.0f, 1.0f);
                acc += GA * fabsf(e - loo);
            }
        }
    }

    // main loop: 2 users per iteration, 6 independent stream loads in flight,
    // 8 independent FMA accumulator chains.
    #pragma unroll 1
    for (int uu = 0; uu < TU; uu += 2) {
        const size_t b0 = (size_t)(ub + uu) * S + s0;
        const size_t b1 = b0 + S;
        int2   m0 = *(const int2*)(train_mask + b0);
        int2   m1 = *(const int2*)(train_mask + b1);
        float2 q0 = *(const float2*)(true_qos + b0);
        float2 q1 = *(const float2*)(true_qos + b1);
        float2 w0 = *(const float2*)(us_lossweight + b0);
        float2 w1 = *(const float2*)(us_lossweight + b1);

        float d00a = 0.f, d00b = 0.f, d01a = 0.f, d01b = 0.f;
        float d10a = 0.f, d10b = 0.f, d11a = 0.f, d11b = 0.f;
        const float4* ur0 = (const float4*)&uemb[uu][0];      // broadcast LDS
        const float4* ur1 = (const float4*)&uemb[uu + 1][0];
        #pragma unroll
        for (int k = 0; k < 8; k += 2) {
            float4 u0a = ur0[k], u0b = ur0[k + 1];
            float4 u1a = ur1[k], u1b = ur1[k + 1];
            d00a += dot4(u0a, ir0[k]); d00b += dot4(u0b, ir0[k + 1]);
            d01a += dot4(u0a, ir1[k]); d01b += dot4(u0b, ir1[k + 1]);
            d10a += dot4(u1a, ir0[k]); d10b += dot4(u1b, ir0[k + 1]);
            d11a += dot4(u1a, ir1[k]); d11b += dot4(u1b, ir1[k + 1]);
        }
        {
            float e = fmaf(d00a + d00b, (float)m0.x, -q0.x);
            acc = fmaf(w0.x * e, e, acc);
            e = fmaf(d01a + d01b, (float)m0.y, -q0.y);
            acc = fmaf(w0.y * e, e, acc);
            e = fmaf(d10a + d10b, (float)m1.x, -q1.x);
            acc = fmaf(w1.x * e, e, acc);
            e = fmaf(d11a + d11b, (float)m1.y, -q1.y);
            acc = fmaf(w1.y * e, e, acc);
        }
    }

    // wave64 reduce + one atomic per block, last block finalizes
    #pragma unroll
    for (int off = 32; off > 0; off >>= 1) acc += __shfl_down(acc, off, 64);
    __shared__ float wp[THREADS / 64];
    int lane = threadIdx.x & 63, wid = threadIdx.x >> 6;
    if (lane == 0) wp[wid] = acc;
    __syncthreads();
    if (threadIdx.x == 0) {
        float t = 0.0f;
        #pragma unroll
        for (int i = 0; i < THREADS / 64; i++) t += wp[i];
        atomicAdd(loss_acc, t);
        __threadfence();
        unsigned int n = atomicAdd(done_counter, 1u);
        if (n == NBLOCKS - 1) {
            out[0] = atomicAdd(loss_acc, 0.0f);  // device-coherent read
        }
    }
}

extern "C" void kernel_launch(void* const* d_in, const int* in_sizes, int n_in,
                              void* d_out, int out_size, void* d_ws, size_t ws_size,
                              hipStream_t stream) {
    const float* user_emb      = (const float*)d_in[0];
    const float* item_emb      = (const float*)d_in[1];
    const int*   train_mask    = (const int*)d_in[2];
    const float* true_qos      = (const float*)d_in[3];
    const float* us_lossweight = (const float*)d_in[4];
    const int*   region_index  = (const int*)d_in[5];
    float* out = (float*)d_out;

    float* ws       = (float*)d_ws;
    float* sums     = ws;                       // R*D
    float* counts   = sums + NUM_REGIONS * D;   // R
    float* loss_acc = counts + NUM_REGIONS;     // 1
    unsigned int* done_counter = (unsigned int*)(loss_acc + 1);

    region_stats_kernel<<<NUM_REGIONS, 256, 0, stream>>>(
        user_emb, region_index, sums, counts, loss_acc, done_counter);

    dim3 grid(GRID_X, GRID_Y);
    mse_kernel<<<grid, THREADS, 0, stream>>>(
        user_emb, item_emb, train_mask, true_qos, us_lossweight,
        region_index, sums, counts, loss_acc, done_counter, out);
}